// Round 4
// baseline (222.480 us; speedup 1.0000x reference)
//
#include <hip/hip_runtime.h>
#include <hip/hip_bf16.h>

#define Bn 4
#define Tn 256
#define Un 64
#define UP1 65
#define Vn 1024
#define Dn 256
#define Hn 256
#define BLANKC 1023
#define NEGF (-1.0e30f)
#define CTCW 0.3f

typedef __attribute__((ext_vector_type(8))) short short8;
typedef __attribute__((ext_vector_type(4))) float f32x4;
typedef __attribute__((ext_vector_type(4))) unsigned int u32x4;

static __device__ __forceinline__ unsigned short f2bf(float f) {
  unsigned int u = __float_as_uint(f);
  u += 0x7FFFu + ((u >> 16) & 1u);
  return (unsigned short)(u >> 16);
}
static __device__ __forceinline__ unsigned int pack2bf(float a, float b) {
  return (unsigned int)f2bf(a) | ((unsigned int)f2bf(b) << 16);
}
static __device__ __forceinline__ float ftanh(float x) {
  float e = __expf(2.0f * x);
  return 1.0f - 2.0f / (e + 1.0f);
}
static __device__ __forceinline__ float laddexp(float a, float b) {
  float m = fmaxf(a, b), n = fminf(a, b);
  return m + __logf(1.0f + __expf(n - m));
}
static __device__ __forceinline__ float laddexp3(float a, float b, float c) {
  float m = fmaxf(fmaxf(a, b), c);
  return m + __logf(__expf(a - m) + __expf(b - m) + __expf(c - m));
}

// ---------------------------------------------------------------------------
// K1 k_prep: bf16 transposes of all four W matrices + zero d_out.
// blocks 0-63: W_out; 64-127: W_ctc; 128-143: W_enc; 144-159: W_dec.
// ---------------------------------------------------------------------------
__global__ __launch_bounds__(256) void k_prep(
    const float* __restrict__ W_enc, const float* __restrict__ W_dec,
    const float* __restrict__ W_out, const float* __restrict__ W_ctc,
    unsigned short* __restrict__ Wt_enc, unsigned short* __restrict__ Wt_dec,
    unsigned short* __restrict__ Wt_out, unsigned short* __restrict__ Wt_ctc,
    float* __restrict__ out) {
  const int blk = blockIdx.x, tid = threadIdx.x;
  if (blk == 0 && tid == 0) out[0] = 0.0f;
  const float* Wsrc;
  unsigned short* Wd;
  int tt, ld;
  if (blk < 64) {
    Wsrc = W_out; Wd = Wt_out; tt = blk; ld = 1024;
  } else if (blk < 128) {
    Wsrc = W_ctc; Wd = Wt_ctc; tt = blk - 64; ld = 1024;
  } else if (blk < 144) {
    Wsrc = W_enc; Wd = Wt_enc; tt = blk - 128; ld = 256;
  } else {
    Wsrc = W_dec; Wd = Wt_dec; tt = blk - 144; ld = 256;
  }
  const int k0 = (tt & 3) * 64, v0 = (tt >> 2) * 64;
  __shared__ float tilebuf[64][65];
#pragma unroll
  for (int rep = 0; rep < 16; ++rep) {
    int e = rep * 256 + tid;
    int rr = e >> 6, cc = e & 63;
    tilebuf[rr][cc] = Wsrc[(k0 + rr) * ld + (v0 + cc)];
  }
  __syncthreads();
#pragma unroll
  for (int rep = 0; rep < 16; ++rep) {
    int e = rep * 256 + tid;
    int rr = e >> 6, cc = e & 63;  // rr: v offset, cc: k offset
    Wd[(v0 + rr) * 256 + (k0 + cc)] = f2bf(tilebuf[cc][rr]);
  }
}

// ---------------------------------------------------------------------------
// K1b k_lin: enc_lin / dec_lin via MFMA. blocks 0-15: enc (1024 rows);
// blocks 16-20: dec (260 rows, clamped/guarded). 64 rows x 256 cols x K=256.
// ---------------------------------------------------------------------------
__global__ __launch_bounds__(256) void k_lin(
    const float* __restrict__ x_enc, const float* __restrict__ x_dec,
    const unsigned short* __restrict__ Wt_enc, const float* __restrict__ b_enc,
    const unsigned short* __restrict__ Wt_dec, const float* __restrict__ b_dec,
    float* __restrict__ enc_lin, float* __restrict__ dec_lin) {
  __shared__ __align__(16) char Asw[64 * 512];
  const int tid = threadIdx.x;
  const int w = tid >> 6, l = tid & 63;
  const int l15 = l & 15, l4 = l >> 4;
  const bool enc = blockIdx.x < 16;
  const int m0 = enc ? blockIdx.x * 64 : (blockIdx.x - 16) * 64;
  const int Mlim = enc ? 1024 : 260;
  const float* xp = enc ? x_enc : x_dec;
  const unsigned short* Wt = enc ? Wt_enc : Wt_dec;
  const float* bias = enc ? b_enc : b_dec;
  float* outp = enc ? enc_lin : dec_lin;

#pragma unroll
  for (int it = 0; it < 8; ++it) {
    int e = (it << 8) + tid;
    int i = e >> 5;
    int k0 = (e & 31) << 3;
    int r = m0 + i;
    if (r > Mlim - 1) r = Mlim - 1;
    const float* sp = xp + r * 256 + k0;
    f32x4 e0 = *(const f32x4*)sp;
    f32x4 e1 = *(const f32x4*)(sp + 4);
    u32x4 pv;
    pv[0] = pack2bf(e0[0], e0[1]);
    pv[1] = pack2bf(e0[2], e0[3]);
    pv[2] = pack2bf(e1[0], e1[1]);
    pv[3] = pack2bf(e1[2], e1[3]);
    int byt = (i << 9) + (k0 << 1);
    byt ^= (i & 7) << 4;
    *(u32x4*)(Asw + byt) = pv;
  }
  __syncthreads();

  const int nb = w * 64;
  f32x4 acc[4][4] = {};
#pragma unroll
  for (int ks = 0; ks < 8; ++ks) {
    int k = ks * 32 + l4 * 8;
    short8 af[4];
#pragma unroll
    for (int mt = 0; mt < 4; ++mt) {
      int i = mt * 16 + l15;
      int byt = (i << 9) + (k << 1);
      byt ^= (i & 7) << 4;
      af[mt] = *(const short8*)(Asw + byt);
    }
    short8 bfr[4];
#pragma unroll
    for (int nt = 0; nt < 4; ++nt) {
      int n = nb + nt * 16 + l15;
      bfr[nt] = *(const short8*)(Wt + n * 256 + k);
    }
#pragma unroll
    for (int mt = 0; mt < 4; ++mt)
#pragma unroll
      for (int nt = 0; nt < 4; ++nt)
        acc[mt][nt] = __builtin_amdgcn_mfma_f32_16x16x32_bf16(
            af[mt], bfr[nt], acc[mt][nt], 0, 0, 0);
  }
  float biasv[4];
#pragma unroll
  for (int nt = 0; nt < 4; ++nt) biasv[nt] = bias[nb + nt * 16 + l15];
#pragma unroll
  for (int mt = 0; mt < 4; ++mt)
#pragma unroll
    for (int rr = 0; rr < 4; ++rr) {
      int row = m0 + mt * 16 + l4 * 4 + rr;
      if (row < Mlim) {
#pragma unroll
        for (int nt = 0; nt < 4; ++nt)
          outp[row * 256 + nb + nt * 16 + l15] = acc[mt][nt][rr] + biasv[nt];
      }
    }
}

// ---------------------------------------------------------------------------
// K2 merged: blocks 0-15 = CTC head; blocks 16-1055 = joiner.
// ks-loop fully unrolled so the compiler pipelines B-fragment global loads
// across MFMAs (the R3 latency stall). No-max softmax, owner-lane gather.
// ---------------------------------------------------------------------------
__global__ __launch_bounds__(256) void k_join2(
    const float* __restrict__ enc_lin, const float* __restrict__ dec_lin,
    const unsigned short* __restrict__ Wt_out, const float* __restrict__ b_out,
    const float* __restrict__ x_enc,
    const unsigned short* __restrict__ Wt_ctc, const float* __restrict__ b_ctc,
    const int* __restrict__ target,
    float* __restrict__ lp_blank, float* __restrict__ lp_label,
    float* __restrict__ ctc_blank, float* __restrict__ ctc_lse,
    float* __restrict__ ctc_lab) {
  __shared__ __align__(16) char Asw[64 * 512];
  __shared__ float s_psum[4][64];
  __shared__ float s_blank[64], s_label[64];
  __shared__ int s_tgt[64];

  const int tid = threadIdx.x;
  const int w = tid >> 6, l = tid & 63;
  const int l15 = l & 15, l4 = l >> 4;

  if (blockIdx.x >= 16) {
    // ---------------- joiner path ----------------
    const int bid = blockIdx.x - 16;
    const int b = bid / 260;
    const int r0 = (bid % 260) * 64;

#pragma unroll
    for (int it = 0; it < 8; ++it) {
      int e = (it << 8) + tid;
      int i = e >> 5;
      int k0 = (e & 31) << 3;
      int r = r0 + i;
      int t = r / 65;
      int u = r - t * 65;
      const float* ep = enc_lin + ((b * Tn + t) * Hn + k0);
      const float* dp = dec_lin + ((b * UP1 + u) * Hn + k0);
      f32x4 e0 = *(const f32x4*)ep;
      f32x4 e1 = *(const f32x4*)(ep + 4);
      f32x4 d0 = *(const f32x4*)dp;
      f32x4 d1 = *(const f32x4*)(dp + 4);
      float h0 = ftanh(e0[0] + d0[0]), h1 = ftanh(e0[1] + d0[1]);
      float h2 = ftanh(e0[2] + d0[2]), h3 = ftanh(e0[3] + d0[3]);
      float h4 = ftanh(e1[0] + d1[0]), h5 = ftanh(e1[1] + d1[1]);
      float h6 = ftanh(e1[2] + d1[2]), h7 = ftanh(e1[3] + d1[3]);
      u32x4 pv;
      pv[0] = pack2bf(h0, h1);
      pv[1] = pack2bf(h2, h3);
      pv[2] = pack2bf(h4, h5);
      pv[3] = pack2bf(h6, h7);
      int byt = (i << 9) + (k0 << 1);
      byt ^= (i & 7) << 4;
      *(u32x4*)(Asw + byt) = pv;
    }
    if (tid < 64) {
      int u = (r0 + tid) % 65;
      s_tgt[tid] = (u < Un) ? target[b * Un + u] : -1;
    }
    __syncthreads();

    float ssum[16];
#pragma unroll
    for (int j = 0; j < 16; ++j) ssum[j] = 0.0f;

#pragma unroll 1
    for (int c = 0; c < 4; ++c) {
      const int nb = c * 256 + w * 64;
      f32x4 acc[4][4] = {};
#pragma unroll
      for (int ks = 0; ks < 8; ++ks) {
        int k = ks * 32 + l4 * 8;
        short8 af[4];
#pragma unroll
        for (int mt = 0; mt < 4; ++mt) {
          int i = mt * 16 + l15;
          int byt = (i << 9) + (k << 1);
          byt ^= (i & 7) << 4;
          af[mt] = *(const short8*)(Asw + byt);
        }
        short8 bfr[4];
#pragma unroll
        for (int nt = 0; nt < 4; ++nt) {
          int n = nb + nt * 16 + l15;
          bfr[nt] = *(const short8*)(Wt_out + n * 256 + k);
        }
#pragma unroll
        for (int mt = 0; mt < 4; ++mt)
#pragma unroll
          for (int nt = 0; nt < 4; ++nt)
            acc[mt][nt] = __builtin_amdgcn_mfma_f32_16x16x32_bf16(
                af[mt], bfr[nt], acc[mt][nt], 0, 0, 0);
      }
      float biasv[4];
#pragma unroll
      for (int nt = 0; nt < 4; ++nt) biasv[nt] = b_out[nb + nt * 16 + l15];
#pragma unroll
      for (int mt = 0; mt < 4; ++mt)
#pragma unroll
        for (int nt = 0; nt < 4; ++nt)
#pragma unroll
          for (int rr = 0; rr < 4; ++rr) acc[mt][nt][rr] += biasv[nt];

      // blank gather: col 1023 lives in c==3, w==3, nt==3, l15==15
      if (c == 3 && w == 3 && l15 == 15) {
#pragma unroll
        for (int mt = 0; mt < 4; ++mt)
#pragma unroll
          for (int rr = 0; rr < 4; ++rr)
            s_blank[mt * 16 + l4 * 4 + rr] = acc[mt][3][rr];
      }
      // label gather: owner-lane decode of target column bits
#pragma unroll
      for (int mt = 0; mt < 4; ++mt)
#pragma unroll
        for (int rr = 0; rr < 4; ++rr) {
          int row = mt * 16 + l4 * 4 + rr;
          int tg = s_tgt[row];
          if ((tg >> 8) == c && ((tg >> 6) & 3) == w && (tg & 15) == l15) {
            int ntv = (tg >> 4) & 3;
            float v01 = (ntv & 1) ? acc[mt][1][rr] : acc[mt][0][rr];
            float v23 = (ntv & 1) ? acc[mt][3][rr] : acc[mt][2][rr];
            s_label[row] = (ntv & 2) ? v23 : v01;
          }
        }

      // exp-sum accumulate (no max: logits bounded ~|20|)
#pragma unroll
      for (int mt = 0; mt < 4; ++mt)
#pragma unroll
        for (int rr = 0; rr < 4; ++rr)
          ssum[mt * 4 + rr] += __expf(acc[mt][0][rr]) + __expf(acc[mt][1][rr]) +
                               __expf(acc[mt][2][rr]) + __expf(acc[mt][3][rr]);
    }

    // one deferred cross-lane reduce (over the 16-lane col group)
#pragma unroll
    for (int ms = 1; ms < 16; ms <<= 1)
#pragma unroll
      for (int j = 0; j < 16; ++j) ssum[j] += __shfl_xor(ssum[j], ms, 64);
    if (l15 == 0) {
#pragma unroll
      for (int j = 0; j < 16; ++j)
        s_psum[w][(j >> 2) * 16 + l4 * 4 + (j & 3)] = ssum[j];
    }
    __syncthreads();

    if (tid < 64) {
      float tot = s_psum[0][tid] + s_psum[1][tid] + s_psum[2][tid] + s_psum[3][tid];
      float lse = __logf(tot);
      int r = r0 + tid;
      int t = r / 65;
      int u = r - t * 65;
      lp_blank[(b * Tn + t) * UP1 + u] = s_blank[tid] - lse;
      if (u < Un) lp_label[(b * Tn + t) * Un + u] = s_label[tid] - lse;
    }
  } else {
    // ---------------- CTC head path ----------------
    const int g0 = blockIdx.x * 64;
    const int b = g0 >> 8;

#pragma unroll
    for (int it = 0; it < 8; ++it) {
      int e = (it << 8) + tid;
      int i = e >> 5;
      int k0 = (e & 31) << 3;
      const float* sp = x_enc + (g0 + i) * Dn + k0;
      f32x4 e0 = *(const f32x4*)sp;
      f32x4 e1 = *(const f32x4*)(sp + 4);
      u32x4 pv;
      pv[0] = pack2bf(e0[0], e0[1]);
      pv[1] = pack2bf(e0[2], e0[3]);
      pv[2] = pack2bf(e1[0], e1[1]);
      pv[3] = pack2bf(e1[2], e1[3]);
      int byt = (i << 9) + (k0 << 1);
      byt ^= (i & 7) << 4;
      *(u32x4*)(Asw + byt) = pv;
    }
    if (tid < 64) s_tgt[tid] = target[b * Un + tid];
    __syncthreads();

    float ssum[16];
#pragma unroll
    for (int j = 0; j < 16; ++j) ssum[j] = 0.0f;

#pragma unroll 1
    for (int c = 0; c < 4; ++c) {
      const int nb = c * 256 + w * 64;
      f32x4 acc[4][4] = {};
#pragma unroll
      for (int ks = 0; ks < 8; ++ks) {
        int k = ks * 32 + l4 * 8;
        short8 af[4];
#pragma unroll
        for (int mt = 0; mt < 4; ++mt) {
          int i = mt * 16 + l15;
          int byt = (i << 9) + (k << 1);
          byt ^= (i & 7) << 4;
          af[mt] = *(const short8*)(Asw + byt);
        }
        short8 bfr[4];
#pragma unroll
        for (int nt = 0; nt < 4; ++nt) {
          int n = nb + nt * 16 + l15;
          bfr[nt] = *(const short8*)(Wt_ctc + n * 256 + k);
        }
#pragma unroll
        for (int mt = 0; mt < 4; ++mt)
#pragma unroll
          for (int nt = 0; nt < 4; ++nt)
            acc[mt][nt] = __builtin_amdgcn_mfma_f32_16x16x32_bf16(
                af[mt], bfr[nt], acc[mt][nt], 0, 0, 0);
      }
      float biasv[4];
#pragma unroll
      for (int nt = 0; nt < 4; ++nt) biasv[nt] = b_ctc[nb + nt * 16 + l15];
#pragma unroll
      for (int mt = 0; mt < 4; ++mt)
#pragma unroll
        for (int nt = 0; nt < 4; ++nt)
#pragma unroll
          for (int rr = 0; rr < 4; ++rr) acc[mt][nt][rr] += biasv[nt];

      if (c == 3 && w == 3 && l15 == 15) {
#pragma unroll
        for (int mt = 0; mt < 4; ++mt)
#pragma unroll
          for (int rr = 0; rr < 4; ++rr)
            s_blank[mt * 16 + l4 * 4 + rr] = acc[mt][3][rr];
      }
      // label gather: raw logits to global; wave-uniform early reject on (c,w)
#pragma unroll 1
      for (int u = 0; u < 64; ++u) {
        int tgu = s_tgt[u];
        if ((tgu >> 8) == c && ((tgu >> 6) & 3) == w) {
          int ntv = (tgu >> 4) & 3;
          if ((tgu & 15) == l15) {
#pragma unroll
            for (int mt = 0; mt < 4; ++mt)
#pragma unroll
              for (int rr = 0; rr < 4; ++rr) {
                float v01 = (ntv & 1) ? acc[mt][1][rr] : acc[mt][0][rr];
                float v23 = (ntv & 1) ? acc[mt][3][rr] : acc[mt][2][rr];
                float v = (ntv & 2) ? v23 : v01;
                ctc_lab[(g0 + mt * 16 + l4 * 4 + rr) * 64 + u] = v;
              }
          }
        }
      }

#pragma unroll
      for (int mt = 0; mt < 4; ++mt)
#pragma unroll
        for (int rr = 0; rr < 4; ++rr)
          ssum[mt * 4 + rr] += __expf(acc[mt][0][rr]) + __expf(acc[mt][1][rr]) +
                               __expf(acc[mt][2][rr]) + __expf(acc[mt][3][rr]);
    }

#pragma unroll
    for (int ms = 1; ms < 16; ms <<= 1)
#pragma unroll
      for (int j = 0; j < 16; ++j) ssum[j] += __shfl_xor(ssum[j], ms, 64);
    if (l15 == 0) {
#pragma unroll
      for (int j = 0; j < 16; ++j)
        s_psum[w][(j >> 2) * 16 + l4 * 4 + (j & 3)] = ssum[j];
    }
    __syncthreads();

    if (tid < 64) {
      float tot = s_psum[0][tid] + s_psum[1][tid] + s_psum[2][tid] + s_psum[3][tid];
      float lse = __logf(tot);
      ctc_blank[g0 + tid] = s_blank[tid] - lse;
      ctc_lse[g0 + tid] = lse;
    }
  }
}

// ---------------------------------------------------------------------------
// K3: blocks 0-3 RNNT anti-diagonal DP; blocks 4-7 CTC DP.
// Register-ring prefetch (PF=12) hides global latency under the laddexp chain.
// CTC labels arrive RAW; normalized here with the prefetched ctc_lse.
// ---------------------------------------------------------------------------
#define PF 12
__global__ __launch_bounds__(64) void k_dp(
    const float* __restrict__ lp_blank, const float* __restrict__ lp_label,
    const float* __restrict__ ctc_blank, const float* __restrict__ ctc_lse,
    const float* __restrict__ ctc_lab,
    const int* __restrict__ target,
    const int* __restrict__ flen, const int* __restrict__ tlen,
    float* __restrict__ out) {
  const int l = threadIdx.x;
  if (blockIdx.x < 4) {
    const int b = blockIdx.x;
    const int ft = flen[b], tl = tlen[b];
    const float* lpb = lp_blank + b * Tn * UP1;
    const float* lpl = lp_label + b * Tn * Un;
    const int dstar = ft - 1 + tl;

    float rb[PF], rl[PF], rb64[PF], rl64[PF];

    auto ldr = [&](int d, int j) {
      int t = d - l;
      int tb = t < 1 ? 1 : (t > 255 ? 255 : t);
      rb[j] = lpb[(tb - 1) * UP1 + l];
      int tc = t < 0 ? 0 : (t > 255 ? 255 : t);
      int lc = l >= 1 ? l - 1 : 0;
      rl[j] = lpl[tc * Un + lc];
      int t64 = d - 64;
      int tb64 = t64 < 1 ? 1 : (t64 > 255 ? 255 : t64);
      rb64[j] = lpb[(tb64 - 1) * UP1 + 64];
      int tc64 = t64 < 0 ? 0 : (t64 > 255 ? 255 : t64);
      rl64[j] = lpl[tc64 * Un + 63];
    };

#pragma unroll
    for (int j = 0; j < PF; ++j) ldr(1 + j, j);

    float a = (l == 0) ? 0.0f : NEGF;
    float a64 = NEGF;
    float cap = NEGF;

    for (int dbase = 1; dbase <= 313; dbase += PF) {
#pragma unroll
      for (int j = 0; j < PF; ++j) {
        const int d = dbase + j;
        float vb = rb[j], vl = rl[j], vb64 = rb64[j], vl64 = rl64[j];
        ldr(d + PF, j);  // issue PF steps ahead
        float aleft = __shfl_up(a, 1, 64);
        int t = d - l;
        bool valid = (t >= 0) && (t < Tn);
        float up = (valid && t >= 1) ? (a + vb) : NEGF;
        float lft = (valid && l >= 1) ? (aleft + vl) : NEGF;
        float nw = valid ? laddexp(up, lft) : NEGF;
        float nw64 = a64;
        if (l == 63) {
          int t64 = d - 64;
          if (t64 >= 0 && t64 < Tn) {
            float up64 = (t64 >= 1) ? (a64 + vb64) : NEGF;
            float l64 = a + vl64;  // old a = alpha[t64][63]
            nw64 = laddexp(up64, l64);
          }
        }
        a = nw;
        if (l == 63) a64 = nw64;
        if (d == dstar) {
          if (l == tl) cap = a;
          if (tl == 64 && l == 63) cap = a64;
        }
      }
    }
    bool owner = (tl < 64) ? (l == tl) : (l == 63);
    if (owner) {
      float ll = cap + lpb[(ft - 1) * UP1 + tl];
      atomicAdd(out, -0.25f * ll);
    }
  } else {
    const int b = blockIdx.x - 4;
    const int ft = flen[b], tl = tlen[b];
    const float* cb = ctc_blank + b * Tn;
    const float* cls = ctc_lse + b * Tn;
    const float* clab = ctc_lab + b * Tn * Un;
    const int tg = target[b * Un + l];
    bool skip1 = (l >= 1) && (tg != target[b * Un + l - 1]);

    float rcb[PF], rcl[PF], rls[PF];
    auto ldc = [&](int t, int j) {
      int tc = t > 255 ? 255 : t;
      rcb[j] = cb[tc];
      rcl[j] = clab[tc * Un + l];
      rls[j] = cls[tc];
    };
#pragma unroll
    for (int j = 0; j < PF; ++j) ldc(1 + j, j);

    float a0 = (l == 0) ? cb[0] : NEGF;
    float a1 = (l == 0) ? (clab[0] - cls[0]) : NEGF;
    float a2 = NEGF;
    for (int tbase = 1; tbase <= 253; tbase += PF) {
#pragma unroll
      for (int j = 0; j < PF; ++j) {
        const int t = tbase + j;
        float eb = rcb[j], e1 = rcl[j] - rls[j];
        ldc(t + PF, j);
        float pm1 = __shfl_up(a1, 1, 64);  // prev[2l-1]
        if (l == 0) pm1 = NEGF;
        float n0 = eb + laddexp(a0, pm1);
        float n1 = e1 + laddexp3(a1, a0, skip1 ? pm1 : NEGF);
        float n2 = a2;
        if (l == 63) n2 = eb + laddexp(a2, a1);
        if (t < ft) {
          a0 = n0;
          a1 = n1;
          a2 = n2;
        }
      }
    }
    __shared__ float cT[129];
    cT[2 * l] = a0;
    cT[2 * l + 1] = a1;
    if (l == 63) cT[128] = a2;
    __syncthreads();
    if (l == 0) {
      int sl = 2 * tl;
      float ll = laddexp(cT[sl], cT[sl - 1]);
      float lb = (ll < NEGF * 0.5f) ? 0.0f : -ll;
      atomicAdd(out, CTCW * 0.25f * lb);
    }
  }
}
#undef PF

// ---------------------------------------------------------------------------
extern "C" void kernel_launch(void* const* d_in, const int* in_sizes, int n_in,
                              void* d_out, int out_size, void* d_ws, size_t ws_size,
                              hipStream_t stream) {
  (void)in_sizes; (void)n_in; (void)out_size; (void)ws_size;
  const float* x_enc = (const float*)d_in[0];
  const float* x_dec = (const float*)d_in[1];
  const float* W_enc = (const float*)d_in[2];
  const float* b_enc = (const float*)d_in[3];
  const float* W_dec = (const float*)d_in[4];
  const float* b_dec = (const float*)d_in[5];
  const float* W_out = (const float*)d_in[6];
  const float* b_out = (const float*)d_in[7];
  const float* W_ctc = (const float*)d_in[8];
  const float* b_ctc = (const float*)d_in[9];
  const int* target = (const int*)d_in[10];
  const int* flen = (const int*)d_in[11];
  const int* tlen = (const int*)d_in[12];

  float* ws = (float*)d_ws;
  float* enc_lin = ws;                    // 262144
  float* dec_lin = ws + 262144;           // 66560
  float* lp_blank = ws + 328704;          // 66560
  float* lp_label = ws + 395264;          // 65536
  float* ctc_blank = ws + 460800;         // 1024
  float* ctc_lse = ws + 461824;           // 1024
  float* ctc_lab = ws + 462848;           // 65536
  unsigned short* Wt_out = (unsigned short*)(ws + 528384);  // 262144 bf16
  unsigned short* Wt_ctc = Wt_out + 262144;                 // 262144 bf16
  // Wt_enc/Wt_dec alias lp_blank/lp_label: live only k_prep->k_lin, while
  // lp_* are written from scratch in k_join2 (stream-ordered, disjoint).
  unsigned short* Wt_enc = (unsigned short*)lp_blank;       // 65536 bf16
  unsigned short* Wt_dec = (unsigned short*)lp_label;       // 65536 bf16
  float* out = (float*)d_out;

  k_prep<<<dim3(160), dim3(256), 0, stream>>>(
      W_enc, W_dec, W_out, W_ctc, Wt_enc, Wt_dec, Wt_out, Wt_ctc, out);
  k_lin<<<dim3(21), dim3(256), 0, stream>>>(
      x_enc, x_dec, Wt_enc, b_enc, Wt_dec, b_dec, enc_lin, dec_lin);
  k_join2<<<dim3(1056), dim3(256), 0, stream>>>(
      enc_lin, dec_lin, Wt_out, b_out, x_enc, Wt_ctc, b_ctc, target,
      lp_blank, lp_label, ctc_blank, ctc_lse, ctc_lab);
  k_dp<<<dim3(8), dim3(64), 0, stream>>>(
      lp_blank, lp_label, ctc_blank, ctc_lse, ctc_lab, target, flen, tlen, out);
}

// Round 5
// 194.290 us; speedup vs baseline: 1.1451x; 1.1451x over previous
//
#include <hip/hip_runtime.h>
#include <hip/hip_bf16.h>

#define Bn 4
#define Tn 256
#define Un 64
#define UP1 65
#define Vn 1024
#define Dn 256
#define Hn 256
#define BLANKC 1023
#define NEGF (-1.0e30f)
#define CTCW 0.3f

typedef __attribute__((ext_vector_type(8))) short short8;
typedef __attribute__((ext_vector_type(4))) float f32x4;
typedef __attribute__((ext_vector_type(4))) unsigned int u32x4;

#define GLD_LDS16(gp, lp)                                                      \
  __builtin_amdgcn_global_load_lds(                                            \
      (const __attribute__((address_space(1))) void*)(gp),                     \
      (__attribute__((address_space(3))) void*)(lp), 16, 0, 0)

static __device__ __forceinline__ unsigned short f2bf(float f) {
  unsigned int u = __float_as_uint(f);
  u += 0x7FFFu + ((u >> 16) & 1u);
  return (unsigned short)(u >> 16);
}
static __device__ __forceinline__ unsigned int pack2bf(float a, float b) {
  return (unsigned int)f2bf(a) | ((unsigned int)f2bf(b) << 16);
}
static __device__ __forceinline__ float ftanh(float x) {
  float e = __expf(2.0f * x);
  return 1.0f - 2.0f / (e + 1.0f);
}
static __device__ __forceinline__ float laddexp(float a, float b) {
  float m = fmaxf(a, b), n = fminf(a, b);
  return m + __logf(1.0f + __expf(n - m));
}
static __device__ __forceinline__ float laddexp3(float a, float b, float c) {
  float m = fmaxf(fmaxf(a, b), c);
  return m + __logf(__expf(a - m) + __expf(b - m) + __expf(c - m));
}
// lane i <- lane i-1 (lane 0 gets 0; callers override lane 0). DPP wave_shr:1.
static __device__ __forceinline__ float shfl_up1(float x) {
  int r = __builtin_amdgcn_update_dpp(0, __float_as_int(x), 0x138, 0xF, 0xF, false);
  return __int_as_float(r);
}

// ---------------------------------------------------------------------------
// K1 k_prep: bf16 transposes of all four W matrices + zero d_out.
// blocks 0-63: W_out; 64-127: W_ctc; 128-143: W_enc; 144-159: W_dec.
// ---------------------------------------------------------------------------
__global__ __launch_bounds__(256) void k_prep(
    const float* __restrict__ W_enc, const float* __restrict__ W_dec,
    const float* __restrict__ W_out, const float* __restrict__ W_ctc,
    unsigned short* __restrict__ Wt_enc, unsigned short* __restrict__ Wt_dec,
    unsigned short* __restrict__ Wt_out, unsigned short* __restrict__ Wt_ctc,
    float* __restrict__ out) {
  const int blk = blockIdx.x, tid = threadIdx.x;
  if (blk == 0 && tid == 0) out[0] = 0.0f;
  const float* Wsrc;
  unsigned short* Wd;
  int tt, ld;
  if (blk < 64) {
    Wsrc = W_out; Wd = Wt_out; tt = blk; ld = 1024;
  } else if (blk < 128) {
    Wsrc = W_ctc; Wd = Wt_ctc; tt = blk - 64; ld = 1024;
  } else if (blk < 144) {
    Wsrc = W_enc; Wd = Wt_enc; tt = blk - 128; ld = 256;
  } else {
    Wsrc = W_dec; Wd = Wt_dec; tt = blk - 144; ld = 256;
  }
  const int k0 = (tt & 3) * 64, v0 = (tt >> 2) * 64;
  __shared__ float tilebuf[64][65];
#pragma unroll
  for (int rep = 0; rep < 16; ++rep) {
    int e = rep * 256 + tid;
    int rr = e >> 6, cc = e & 63;
    tilebuf[rr][cc] = Wsrc[(k0 + rr) * ld + (v0 + cc)];
  }
  __syncthreads();
#pragma unroll
  for (int rep = 0; rep < 16; ++rep) {
    int e = rep * 256 + tid;
    int rr = e >> 6, cc = e & 63;  // rr: v offset, cc: k offset
    Wd[(v0 + rr) * 256 + (k0 + cc)] = f2bf(tilebuf[cc][rr]);
  }
}

// ---------------------------------------------------------------------------
// K1b k_lin: enc_lin / dec_lin via MFMA (unchanged from R4 — tiny kernel).
// ---------------------------------------------------------------------------
__global__ __launch_bounds__(256) void k_lin(
    const float* __restrict__ x_enc, const float* __restrict__ x_dec,
    const unsigned short* __restrict__ Wt_enc, const float* __restrict__ b_enc,
    const unsigned short* __restrict__ Wt_dec, const float* __restrict__ b_dec,
    float* __restrict__ enc_lin, float* __restrict__ dec_lin) {
  __shared__ __align__(16) char Asw[64 * 512];
  const int tid = threadIdx.x;
  const int w = tid >> 6, l = tid & 63;
  const int l15 = l & 15, l4 = l >> 4;
  const bool enc = blockIdx.x < 16;
  const int m0 = enc ? blockIdx.x * 64 : (blockIdx.x - 16) * 64;
  const int Mlim = enc ? 1024 : 260;
  const float* xp = enc ? x_enc : x_dec;
  const unsigned short* Wt = enc ? Wt_enc : Wt_dec;
  const float* bias = enc ? b_enc : b_dec;
  float* outp = enc ? enc_lin : dec_lin;

#pragma unroll
  for (int it = 0; it < 8; ++it) {
    int e = (it << 8) + tid;
    int i = e >> 5;
    int k0 = (e & 31) << 3;
    int r = m0 + i;
    if (r > Mlim - 1) r = Mlim - 1;
    const float* sp = xp + r * 256 + k0;
    f32x4 e0 = *(const f32x4*)sp;
    f32x4 e1 = *(const f32x4*)(sp + 4);
    u32x4 pv;
    pv[0] = pack2bf(e0[0], e0[1]);
    pv[1] = pack2bf(e0[2], e0[3]);
    pv[2] = pack2bf(e1[0], e1[1]);
    pv[3] = pack2bf(e1[2], e1[3]);
    int byt = (i << 9) + (k0 << 1);
    byt ^= (i & 7) << 4;
    *(u32x4*)(Asw + byt) = pv;
  }
  __syncthreads();

  const int nb = w * 64;
  f32x4 acc[4][4] = {};
#pragma unroll
  for (int ks = 0; ks < 8; ++ks) {
    int k = ks * 32 + l4 * 8;
    short8 af[4];
#pragma unroll
    for (int mt = 0; mt < 4; ++mt) {
      int i = mt * 16 + l15;
      int byt = (i << 9) + (k << 1);
      byt ^= (i & 7) << 4;
      af[mt] = *(const short8*)(Asw + byt);
    }
    short8 bfr[4];
#pragma unroll
    for (int nt = 0; nt < 4; ++nt) {
      int n = nb + nt * 16 + l15;
      bfr[nt] = *(const short8*)(Wt + n * 256 + k);
    }
#pragma unroll
    for (int mt = 0; mt < 4; ++mt)
#pragma unroll
      for (int nt = 0; nt < 4; ++nt)
        acc[mt][nt] = __builtin_amdgcn_mfma_f32_16x16x32_bf16(
            af[mt], bfr[nt], acc[mt][nt], 0, 0, 0);
  }
  float biasv[4];
#pragma unroll
  for (int nt = 0; nt < 4; ++nt) biasv[nt] = bias[nb + nt * 16 + l15];
#pragma unroll
  for (int mt = 0; mt < 4; ++mt)
#pragma unroll
    for (int rr = 0; rr < 4; ++rr) {
      int row = m0 + mt * 16 + l4 * 4 + rr;
      if (row < Mlim) {
#pragma unroll
        for (int nt = 0; nt < 4; ++nt)
          outp[row * 256 + nb + nt * 16 + l15] = acc[mt][nt][rr] + biasv[nt];
      }
    }
}

// ---------------------------------------------------------------------------
// K2 merged: blocks 0-15 = CTC head; blocks 16-1055 = joiner.
// B staged per (c,ks)-step through a 2x16KB LDS double-buffer via
// global_load_lds (T3 minimum 2-phase: stage(next) -> ds_read cur + MFMA ->
// barrier). B-tile XOR-swizzled: linear LDS dest + inverse-swizzled global
// source + swizzled ds_read (both-sides rule). 2-way bank aliasing only.
// ---------------------------------------------------------------------------
__global__ __launch_bounds__(256, 2) void k_join2(
    const float* __restrict__ enc_lin, const float* __restrict__ dec_lin,
    const unsigned short* __restrict__ Wt_out, const float* __restrict__ b_out,
    const float* __restrict__ x_enc,
    const unsigned short* __restrict__ Wt_ctc, const float* __restrict__ b_ctc,
    const int* __restrict__ target,
    float* __restrict__ lp_blank, float* __restrict__ lp_label,
    float* __restrict__ ctc_blank, float* __restrict__ ctc_lse,
    float* __restrict__ ctc_lab) {
  __shared__ __align__(16) char Asw[64 * 512];    // 32KB A tile
  __shared__ __align__(16) char Bsw[2 * 16384];   // 2 x 16KB B step buffers
  __shared__ float s_psum[4][64];
  __shared__ float s_blank[64], s_label[64];
  __shared__ int s_tgt[64];

  const int tid = threadIdx.x;
  const int w = tid >> 6, l = tid & 63;
  const int l15 = l & 15, l4 = l >> 4;

  // Per-thread constant staging decode: p16 = r*256+tid; canonical col/off
  // of the swizzled slot this thread's gload_lds lane-slot holds.
  int colterm[4];  // element offset within a (c-chunk, ks-step): col*256 + off*8
  int dstoff[4];   // wave-uniform LDS byte base per round
#pragma unroll
  for (int r = 0; r < 4; ++r) {
    int p16 = r * 256 + tid;
    int col = ((p16 >> 3) << 1) | (((p16 >> 2) ^ (p16 >> 4)) & 1);
    int off = (p16 & 3) ^ (col & 3);
    colterm[r] = col * 256 + off * 8;
    dstoff[r] = r * 4096 + (w << 10);
  }

  const bool joiner = blockIdx.x >= 16;
  const unsigned short* Wt = joiner ? Wt_out : Wt_ctc;
  const float* bias = joiner ? b_out : b_ctc;

  auto stageB = [&](int cc, int kss, int buf) {
#pragma unroll
    for (int r = 0; r < 4; ++r) {
      const unsigned short* src = Wt + cc * 65536 + kss * 32 + colterm[r];
      GLD_LDS16(src, Bsw + buf * 16384 + dstoff[r]);
    }
  };

  int b, r0 = 0, g0 = 0;
  if (joiner) {
    const int bid = blockIdx.x - 16;
    b = bid / 260;
    r0 = (bid % 260) * 64;
    // A = tanh(enc+dec) -> bf16 swizzled LDS
#pragma unroll
    for (int it = 0; it < 8; ++it) {
      int e = (it << 8) + tid;
      int i = e >> 5;
      int k0 = (e & 31) << 3;
      int r = r0 + i;
      int t = r / 65;
      int u = r - t * 65;
      const float* ep = enc_lin + ((b * Tn + t) * Hn + k0);
      const float* dp = dec_lin + ((b * UP1 + u) * Hn + k0);
      f32x4 e0 = *(const f32x4*)ep;
      f32x4 e1 = *(const f32x4*)(ep + 4);
      f32x4 d0 = *(const f32x4*)dp;
      f32x4 d1 = *(const f32x4*)(dp + 4);
      u32x4 pv;
      pv[0] = pack2bf(ftanh(e0[0] + d0[0]), ftanh(e0[1] + d0[1]));
      pv[1] = pack2bf(ftanh(e0[2] + d0[2]), ftanh(e0[3] + d0[3]));
      pv[2] = pack2bf(ftanh(e1[0] + d1[0]), ftanh(e1[1] + d1[1]));
      pv[3] = pack2bf(ftanh(e1[2] + d1[2]), ftanh(e1[3] + d1[3]));
      int byt = (i << 9) + (k0 << 1);
      byt ^= (i & 7) << 4;
      *(u32x4*)(Asw + byt) = pv;
    }
    if (tid < 64) {
      int u = (r0 + tid) % 65;
      s_tgt[tid] = (u < Un) ? target[b * Un + u] : -1;
    }
  } else {
    g0 = blockIdx.x * 64;
    b = g0 >> 8;
#pragma unroll
    for (int it = 0; it < 8; ++it) {
      int e = (it << 8) + tid;
      int i = e >> 5;
      int k0 = (e & 31) << 3;
      const float* sp = x_enc + (g0 + i) * Dn + k0;
      f32x4 e0 = *(const f32x4*)sp;
      f32x4 e1 = *(const f32x4*)(sp + 4);
      u32x4 pv;
      pv[0] = pack2bf(e0[0], e0[1]);
      pv[1] = pack2bf(e0[2], e0[3]);
      pv[2] = pack2bf(e1[0], e1[1]);
      pv[3] = pack2bf(e1[2], e1[3]);
      int byt = (i << 9) + (k0 << 1);
      byt ^= (i & 7) << 4;
      *(u32x4*)(Asw + byt) = pv;
    }
    if (tid < 64) s_tgt[tid] = target[b * Un + tid];
  }
  stageB(0, 0, 0);
  __syncthreads();  // drains LDS writes (A) + vmcnt (B step 0)

  float ssum[16];
#pragma unroll
  for (int j = 0; j < 16; ++j) ssum[j] = 0.0f;

#pragma unroll 1
  for (int c = 0; c < 4; ++c) {
    const int nb = c * 256 + w * 64;
    f32x4 acc[4][4] = {};
#pragma unroll
    for (int ks = 0; ks < 8; ++ks) {
      // prefetch next step into the other buffer (buf parity = ks parity)
      if (ks < 7) stageB(c, ks + 1, (ks + 1) & 1);
      else if (c < 3) stageB(c + 1, 0, 0);
      const int k = ks * 32 + l4 * 8;
      short8 af[4];
#pragma unroll
      for (int mt = 0; mt < 4; ++mt) {
        int i = mt * 16 + l15;
        int byt = (i << 9) + (k << 1);
        byt ^= (i & 7) << 4;
        af[mt] = *(const short8*)(Asw + byt);
      }
      short8 bfr[4];
#pragma unroll
      for (int nt = 0; nt < 4; ++nt) {
        int coln = w * 64 + nt * 16 + l15;
        int byt = (ks & 1) * 16384 + ((coln * 64 + l4 * 16) ^ ((coln & 7) << 4));
        bfr[nt] = *(const short8*)(Bsw + byt);
      }
#pragma unroll
      for (int mt = 0; mt < 4; ++mt)
#pragma unroll
        for (int nt = 0; nt < 4; ++nt)
          acc[mt][nt] = __builtin_amdgcn_mfma_f32_16x16x32_bf16(
              af[mt], bfr[nt], acc[mt][nt], 0, 0, 0);
      __syncthreads();  // drains prefetch vmcnt; next iter's buffer ready
    }
    float biasv[4];
#pragma unroll
    for (int nt = 0; nt < 4; ++nt) biasv[nt] = bias[nb + nt * 16 + l15];
#pragma unroll
    for (int mt = 0; mt < 4; ++mt)
#pragma unroll
      for (int nt = 0; nt < 4; ++nt)
#pragma unroll
        for (int rr = 0; rr < 4; ++rr) acc[mt][nt][rr] += biasv[nt];

    if (joiner) {
      // blank: col 1023 = (c3,w3,nt3,l15==15)
      if (c == 3 && w == 3 && l15 == 15) {
#pragma unroll
        for (int mt = 0; mt < 4; ++mt)
#pragma unroll
          for (int rr = 0; rr < 4; ++rr)
            s_blank[mt * 16 + l4 * 4 + rr] = acc[mt][3][rr];
      }
#pragma unroll
      for (int mt = 0; mt < 4; ++mt)
#pragma unroll
        for (int rr = 0; rr < 4; ++rr) {
          int row = mt * 16 + l4 * 4 + rr;
          int tg = s_tgt[row];
          if ((tg >> 8) == c && ((tg >> 6) & 3) == w && (tg & 15) == l15) {
            int ntv = (tg >> 4) & 3;
            float v01 = (ntv & 1) ? acc[mt][1][rr] : acc[mt][0][rr];
            float v23 = (ntv & 1) ? acc[mt][3][rr] : acc[mt][2][rr];
            s_label[row] = (ntv & 2) ? v23 : v01;
          }
        }
    } else {
      if (c == 3 && w == 3 && l15 == 15) {
#pragma unroll
        for (int mt = 0; mt < 4; ++mt)
#pragma unroll
          for (int rr = 0; rr < 4; ++rr)
            s_blank[mt * 16 + l4 * 4 + rr] = acc[mt][3][rr];
      }
#pragma unroll 1
      for (int u = 0; u < 64; ++u) {
        int tgu = s_tgt[u];
        if ((tgu >> 8) == c && ((tgu >> 6) & 3) == w) {
          int ntv = (tgu >> 4) & 3;
          if ((tgu & 15) == l15) {
#pragma unroll
            for (int mt = 0; mt < 4; ++mt)
#pragma unroll
              for (int rr = 0; rr < 4; ++rr) {
                float v01 = (ntv & 1) ? acc[mt][1][rr] : acc[mt][0][rr];
                float v23 = (ntv & 1) ? acc[mt][3][rr] : acc[mt][2][rr];
                float v = (ntv & 2) ? v23 : v01;
                ctc_lab[(g0 + mt * 16 + l4 * 4 + rr) * 64 + u] = v;
              }
          }
        }
      }
    }
    // exp-sum accumulate (no-max softmax: |logit| bounded ~20)
#pragma unroll
    for (int mt = 0; mt < 4; ++mt)
#pragma unroll
      for (int rr = 0; rr < 4; ++rr)
        ssum[mt * 4 + rr] += __expf(acc[mt][0][rr]) + __expf(acc[mt][1][rr]) +
                             __expf(acc[mt][2][rr]) + __expf(acc[mt][3][rr]);
  }

#pragma unroll
  for (int ms = 1; ms < 16; ms <<= 1)
#pragma unroll
    for (int j = 0; j < 16; ++j) ssum[j] += __shfl_xor(ssum[j], ms, 64);
  if (l15 == 0) {
#pragma unroll
    for (int j = 0; j < 16; ++j)
      s_psum[w][(j >> 2) * 16 + l4 * 4 + (j & 3)] = ssum[j];
  }
  __syncthreads();

  if (tid < 64) {
    float tot = s_psum[0][tid] + s_psum[1][tid] + s_psum[2][tid] + s_psum[3][tid];
    float lse = __logf(tot);
    if (joiner) {
      int r = r0 + tid;
      int t = r / 65;
      int u = r - t * 65;
      lp_blank[(b * Tn + t) * UP1 + u] = s_blank[tid] - lse;
      if (u < Un) lp_label[(b * Tn + t) * Un + u] = s_label[tid] - lse;
    } else {
      ctc_blank[g0 + tid] = s_blank[tid] - lse;
      ctc_lse[g0 + tid] = lse;
    }
  }
}

// ---------------------------------------------------------------------------
// K3 k_dp: blocks 0-3 RNNT anti-diagonal DP; blocks 4-7 CTC DP.
// All DP inputs bulk-preloaded to LDS by 4 waves (one vmcnt drain); wave 0
// runs the chain from LDS. shfl_up -> DPP wave_shr:1 (VALU-rate, no
// ds_permute latency on the serial chain).
// ---------------------------------------------------------------------------
__global__ __launch_bounds__(256) void k_dp(
    const float* __restrict__ lp_blank, const float* __restrict__ lp_label,
    const float* __restrict__ ctc_blank, const float* __restrict__ ctc_lse,
    const float* __restrict__ ctc_lab,
    const int* __restrict__ target,
    const int* __restrict__ flen, const int* __restrict__ tlen,
    float* __restrict__ out) {
  __shared__ __align__(16) float sA[16640];  // RNNT lp_blank[t][u]
  __shared__ __align__(16) float sB[16384];  // RNNT lp_label / CTC raw labels
  __shared__ float sC[256], sD[256];         // CTC blank / lse
  __shared__ float cT[129];
  const int tid = threadIdx.x;
  const int l = tid & 63;

  if (blockIdx.x < 4) {
    const int b = blockIdx.x;
    {
      const f32x4* g1 = (const f32x4*)(lp_blank + b * 16640);
      f32x4* s1 = (f32x4*)sA;
      for (int i = tid; i < 4160; i += 256) s1[i] = g1[i];
      const f32x4* g2 = (const f32x4*)(lp_label + b * 16384);
      f32x4* s2 = (f32x4*)sB;
      for (int i = tid; i < 4096; i += 256) s2[i] = g2[i];
    }
    __syncthreads();
    if (tid < 64) {
      const int ft = flen[b], tl = tlen[b];
      const int dstar = ft - 1 + tl;
      float a = (l == 0) ? 0.0f : NEGF;
      float a64 = NEGF, cap = NEGF;
      for (int d0 = 1; d0 <= 313; d0 += 8) {  // d up to 320 >= 319; pad neutral
#pragma unroll
        for (int j = 0; j < 8; ++j) {
          const int d = d0 + j;
          float aleft = shfl_up1(a);
          int t = d - l;
          int tb = t < 1 ? 1 : (t > 255 ? 255 : t);
          float vb = sA[(tb - 1) * 65 + l];
          int tc = t < 0 ? 0 : (t > 255 ? 255 : t);
          float vl = sB[tc * 64 + (l >= 1 ? l - 1 : 0)];
          bool valid = (t >= 0) && (t < Tn);
          float up = (valid && t >= 1) ? (a + vb) : NEGF;
          float lft = (valid && l >= 1) ? (aleft + vl) : NEGF;
          float nw = valid ? laddexp(up, lft) : NEGF;
          float nw64 = a64;
          if (l == 63) {
            int t64 = d - 64;
            if (t64 >= 0 && t64 < Tn) {
              int tb64 = t64 < 1 ? 1 : t64;
              float up64 = (t64 >= 1) ? (a64 + sA[(tb64 - 1) * 65 + 64]) : NEGF;
              nw64 = laddexp(up64, a + sB[t64 * 64 + 63]);
            }
          }
          a = nw;
          if (l == 63) a64 = nw64;
          if (d == dstar) {
            if (l == tl) cap = a;
            if (tl == 64 && l == 63) cap = a64;
          }
        }
      }
      bool owner = (tl < 64) ? (l == tl) : (l == 63);
      if (owner) atomicAdd(out, -0.25f * (cap + sA[(ft - 1) * 65 + tl]));
    }
  } else {
    const int b = blockIdx.x - 4;
    {
      const f32x4* g2 = (const f32x4*)(ctc_lab + b * 16384);
      f32x4* s2 = (f32x4*)sB;
      for (int i = tid; i < 4096; i += 256) s2[i] = g2[i];
      sC[tid] = ctc_blank[b * 256 + tid];
      sD[tid] = ctc_lse[b * 256 + tid];
    }
    __syncthreads();
    if (tid < 64) {
      const int ft = flen[b], tl = tlen[b];
      const int tg = target[b * Un + l];
      bool skip1 = (l >= 1) && (tg != target[b * Un + l - 1]);
      float a0 = (l == 0) ? sC[0] : NEGF;
      float a1 = (l == 0) ? (sB[0] - sD[0]) : NEGF;
      float a2 = NEGF;
      for (int t0 = 1; t0 <= 249; t0 += 8) {  // t up to 256; pad frozen (t>=ft)
#pragma unroll
        for (int j = 0; j < 8; ++j) {
          const int t = t0 + j;
          int tc = t > 255 ? 255 : t;
          float eb = sC[tc];
          float e1 = sB[tc * 64 + l] - sD[tc];
          float pm1 = shfl_up1(a1);
          if (l == 0) pm1 = NEGF;
          float n0 = eb + laddexp(a0, pm1);
          float n1 = e1 + laddexp3(a1, a0, skip1 ? pm1 : NEGF);
          float n2 = a2;
          if (l == 63) n2 = eb + laddexp(a2, a1);
          if (t < ft) {
            a0 = n0;
            a1 = n1;
            a2 = n2;
          }
        }
      }
      cT[2 * l] = a0;
      cT[2 * l + 1] = a1;
      if (l == 63) cT[128] = a2;
      __builtin_amdgcn_s_waitcnt(0);  // lgkm drain before lane-0 readback
      if (l == 0) {
        int sl = 2 * tl;
        float ll = laddexp(cT[sl], cT[sl - 1]);
        float lb = (ll < NEGF * 0.5f) ? 0.0f : -ll;
        atomicAdd(out, CTCW * 0.25f * lb);
      }
    }
  }
}

// ---------------------------------------------------------------------------
extern "C" void kernel_launch(void* const* d_in, const int* in_sizes, int n_in,
                              void* d_out, int out_size, void* d_ws, size_t ws_size,
                              hipStream_t stream) {
  (void)in_sizes; (void)n_in; (void)out_size; (void)ws_size;
  const float* x_enc = (const float*)d_in[0];
  const float* x_dec = (const float*)d_in[1];
  const float* W_enc = (const float*)d_in[2];
  const float* b_enc = (const float*)d_in[3];
  const float* W_dec = (const float*)d_in[4];
  const float* b_dec = (const float*)d_in[5];
  const float* W_out = (const float*)d_in[6];
  const float* b_out = (const float*)d_in[7];
  const float* W_ctc = (const float*)d_in[8];
  const float* b_ctc = (const float*)d_in[9];
  const int* target = (const int*)d_in[10];
  const int* flen = (const int*)d_in[11];
  const int* tlen = (const int*)d_in[12];

  float* ws = (float*)d_ws;
  float* enc_lin = ws;                    // 262144
  float* dec_lin = ws + 262144;           // 66560
  float* lp_blank = ws + 328704;          // 66560
  float* lp_label = ws + 395264;          // 65536
  float* ctc_blank = ws + 460800;         // 1024
  float* ctc_lse = ws + 461824;           // 1024
  float* ctc_lab = ws + 462848;           // 65536
  unsigned short* Wt_out = (unsigned short*)(ws + 528384);  // 262144 bf16
  unsigned short* Wt_ctc = Wt_out + 262144;                 // 262144 bf16
  // Wt_enc/Wt_dec alias lp_blank/lp_label (disjoint lifetimes).
  unsigned short* Wt_enc = (unsigned short*)lp_blank;       // 65536 bf16
  unsigned short* Wt_dec = (unsigned short*)lp_label;       // 65536 bf16
  float* out = (float*)d_out;

  k_prep<<<dim3(160), dim3(256), 0, stream>>>(
      W_enc, W_dec, W_out, W_ctc, Wt_enc, Wt_dec, Wt_out, Wt_ctc, out);
  k_lin<<<dim3(21), dim3(256), 0, stream>>>(
      x_enc, x_dec, Wt_enc, b_enc, Wt_dec, b_dec, enc_lin, dec_lin);
  k_join2<<<dim3(1056), dim3(256), 0, stream>>>(
      enc_lin, dec_lin, Wt_out, b_out, x_enc, Wt_ctc, b_ctc, target,
      lp_blank, lp_label, ctc_blank, ctc_lse, ctc_lab);
  k_dp<<<dim3(8), dim3(64 * 4), 0, stream>>>(
      lp_blank, lp_label, ctc_blank, ctc_lse, ctc_lab, target, flen, tlen, out);
}